// Round 6
// baseline (197.357 us; speedup 1.0000x reference)
//
#include <hip/hip_runtime.h>
#include <hip/hip_bf16.h>
#include <stdint.h>

#define B_ 8192
#define IN_ 1024
#define H_ 1024
#define OUT_ 512
#define KC 2048   // IN_+H_
#define N4 4096   // 4*H_

typedef __bf16 bf16_t;
typedef __bf16 bf16x8 __attribute__((ext_vector_type(8)));
typedef float f32x4 __attribute__((ext_vector_type(4)));

__device__ __forceinline__ void gload_lds16(const void* g, void* l) {
  __builtin_amdgcn_global_load_lds(
      (const __attribute__((address_space(1))) uint32_t*)g,
      (__attribute__((address_space(3))) uint32_t*)l, 16, 0, 0);
}

__device__ __forceinline__ float fsigmoid(float x) {
  return __builtin_amdgcn_rcpf(1.0f + __expf(-x));
}
__device__ __forceinline__ float ftanh(float x) {
  return 2.0f * __builtin_amdgcn_rcpf(1.0f + __expf(-2.0f * x)) - 1.0f;
}

// ---------------- pack kernels ----------------

__global__ __launch_bounds__(256) void pack_combined(
    const float* __restrict__ x, const float* __restrict__ h,
    bf16_t* __restrict__ out) {
  const int row = blockIdx.x;
  const int j = threadIdx.x * 8;
  const float* src = (j < IN_) ? (x + (size_t)row * IN_ + j)
                               : (h + (size_t)row * H_ + (j - IN_));
  float4 a = ((const float4*)src)[0];
  float4 b = ((const float4*)src)[1];
  bf16x8 v;
  v[0] = (bf16_t)a.x; v[1] = (bf16_t)a.y; v[2] = (bf16_t)a.z; v[3] = (bf16_t)a.w;
  v[4] = (bf16_t)b.x; v[5] = (bf16_t)b.y; v[6] = (bf16_t)b.z; v[7] = (bf16_t)b.w;
  *(bf16x8*)(out + (size_t)row * KC + j) = v;
}

// Transpose all 4 gate weights in one launch: dst[(n*4+g)][k] = Wg[k][n].
__global__ __launch_bounds__(256) void transpose_pack4(
    const float* __restrict__ Wi, const float* __restrict__ Wf,
    const float* __restrict__ Wo, const float* __restrict__ Wc,
    bf16_t* __restrict__ dst) {
  const int g = blockIdx.z;
  const float* src = (g == 0) ? Wi : (g == 1) ? Wf : (g == 2) ? Wo : Wc;
  __shared__ float tile[64][65];
  const int k0 = blockIdx.y * 64, n0 = blockIdx.x * 64;
  const int t = threadIdx.x;
  const int tr = t >> 4, tc4 = (t & 15) * 4;
#pragma unroll
  for (int r = 0; r < 4; ++r) {
    const int k = tr + r * 16;
    float4 v = *(const float4*)(src + (size_t)(k0 + k) * H_ + n0 + tc4);
    tile[k][tc4] = v.x; tile[k][tc4 + 1] = v.y;
    tile[k][tc4 + 2] = v.z; tile[k][tc4 + 3] = v.w;
  }
  __syncthreads();
  const int nr = t >> 3, kc8 = (t & 7) * 8;
#pragma unroll
  for (int r = 0; r < 2; ++r) {
    const int n = nr + r * 32;
    bf16x8 v;
#pragma unroll
    for (int q = 0; q < 8; ++q) v[q] = (bf16_t)tile[kc8 + q][n];
    *(bf16x8*)(dst + (size_t)((n0 + n) * 4 + g) * KC + k0 + kc8) = v;
  }
}

// Generic single-matrix transpose-pack (for Wy). dst[n][k] = src[k][n].
__global__ __launch_bounds__(256) void transpose_pack(
    const float* __restrict__ src, bf16_t* __restrict__ dst, int K, int N) {
  __shared__ float tile[64][65];
  const int k0 = blockIdx.y * 64, n0 = blockIdx.x * 64;
  const int t = threadIdx.x;
  const int tr = t >> 4, tc4 = (t & 15) * 4;
#pragma unroll
  for (int r = 0; r < 4; ++r) {
    const int k = tr + r * 16;
    float4 v = *(const float4*)(src + (size_t)(k0 + k) * N + n0 + tc4);
    tile[k][tc4] = v.x; tile[k][tc4 + 1] = v.y;
    tile[k][tc4 + 2] = v.z; tile[k][tc4 + 3] = v.w;
  }
  __syncthreads();
  const int nr = t >> 3, kc8 = (t & 7) * 8;
#pragma unroll
  for (int r = 0; r < 2; ++r) {
    const int n = nr + r * 32;
    bf16x8 v;
#pragma unroll
    for (int q = 0; q < 8; ++q) v[q] = (bf16_t)tile[kc8 + q][n];
    *(bf16x8*)(dst + (size_t)(n0 + n) * K + k0 + kc8) = v;
  }
}

// ---------------- GEMM1: 256x256 8-phase (m201) + kk-outer MFMA ------------
// gates = A[M][K] * Wt[N][K]^T with Wt rows n' = hcol*4 + g (gate-interleaved)
__global__ __launch_bounds__(512) void gemm1_8ph(
    const bf16_t* __restrict__ A, const bf16_t* __restrict__ Bt,
    const float* __restrict__ c_in,
    const float* __restrict__ bi, const float* __restrict__ bfg,
    const float* __restrict__ bo, const float* __restrict__ bc,
    float* __restrict__ h_out, float* __restrict__ c_out,
    bf16_t* __restrict__ hb) {
  constexpr int K = KC;
  constexpr int NT = K / 64;  // 32 K-tiles
  __shared__ char lds[131072];

  const int tid = threadIdx.x;
  const int lane = tid & 63;
  const int w = tid >> 6;
  const int wr = w >> 2, wc = w & 3;
  const int l15 = lane & 15, l4 = lane >> 4;

  // XCD-bijective swizzle: 512 blocks, 8 XCDs, 64 blocks/XCD.
  const int wg = blockIdx.x;
  const int swz = (wg & 7) * 64 + (wg >> 3);
  const int bx = swz >> 5;   // 0..15
  const int by = swz & 31;   // 0..31
  const int m0 = by * 256, n0 = bx * 256;

  // ---- staging: per-lane pre-swizzled global source ----
  const int jrow = lane >> 2;
  const int jcol = ((lane & 3) * 16) ^ ((lane >> 5) << 5);
  const char* Asrc = (const char*)A + (size_t)(m0 + w * 16 + jrow) * (K * 2) + jcol;
  const char* Bsrc = (const char*)Bt + (size_t)(n0 + w * 16 + jrow) * (K * 2) + jcol;
  char* ldsA = lds;
  char* ldsB = lds + 32768;
  const int wchunk = w * 2048;

#define STG_A(buf, h, tt) do {                                            \
    gload_lds16(Asrc + (size_t)(h) * 128 * (K * 2) + (size_t)(tt) * 128,  \
                ldsA + (buf) * 65536 + (h) * 16384 + wchunk);             \
    gload_lds16(Asrc + (size_t)(h) * 128 * (K * 2) + (size_t)(tt) * 128 + 64, \
                ldsA + (buf) * 65536 + (h) * 16384 + wchunk + 1024);      \
  } while (0)
#define STG_B(buf, h, tt) do {                                            \
    gload_lds16(Bsrc + (size_t)(h) * 128 * (K * 2) + (size_t)(tt) * 128,  \
                ldsB + (buf) * 65536 + (h) * 16384 + wchunk);             \
    gload_lds16(Bsrc + (size_t)(h) * 128 * (K * 2) + (size_t)(tt) * 128 + 64, \
                ldsB + (buf) * 65536 + (h) * 16384 + wchunk + 1024);      \
  } while (0)

  const int rdoff = l15 * 64 + ((l4 * 16) ^ ((l15 >> 3) << 5));
  const char* ldsArd = lds + wr * 16384 + rdoff;
  const char* ldsBrd = lds + 32768 + (wc >> 1) * 16384 + (wc & 1) * 8192 + rdoff;

  f32x4 acc[8][4] = {};
  bf16x8 fa[4][2], fb[4][2];

  // kk-OUTER: 8 independent MFMAs per round; round 2 deps at distance 8.
#define MFMA_Q(MIBASE, NIBASE)                                                \
  do {                                                                        \
    __builtin_amdgcn_s_setprio(1);                                            \
    _Pragma("unroll") for (int kk = 0; kk < 2; ++kk)                          \
        _Pragma("unroll") for (int mi = 0; mi < 4; ++mi)                      \
            _Pragma("unroll") for (int ni = 0; ni < 2; ++ni)                  \
                acc[(MIBASE) + mi][(NIBASE) + ni] =                           \
                    __builtin_amdgcn_mfma_f32_16x16x32_bf16(                  \
                        fa[mi][kk], fb[(NIBASE) + ni][kk],                    \
                        acc[(MIBASE) + mi][(NIBASE) + ni], 0, 0, 0);          \
    __builtin_amdgcn_s_setprio(0);                                            \
  } while (0)

  // ---- prologue: tile0 complete + tile1 {B0,A0,A1} in flight ----
  STG_B(0, 0, 0); STG_A(0, 0, 0); STG_A(0, 1, 0); STG_B(0, 1, 0);
  STG_B(1, 0, 1); STG_A(1, 0, 1); STG_A(1, 1, 1);
  asm volatile("s_waitcnt vmcnt(6)" ::: "memory");  // tile0's 8 loads landed
  __builtin_amdgcn_s_barrier();

  for (int t = 0; t < NT; ++t) {
    const int buf = t & 1;
    const int nbuf = buf ^ 1;
    const char* ard = ldsArd + buf * 65536;
    const char* brd = ldsBrd + buf * 65536;
    const bool st1 = (t + 1 < NT);
    const bool st2 = (t + 2 < NT);

    // P1: (m-lo, n-lo); 12 ds_reads
#pragma unroll
    for (int mi = 0; mi < 4; ++mi)
#pragma unroll
      for (int kk = 0; kk < 2; ++kk)
        fa[mi][kk] = *(const bf16x8*)(ard + mi * 2048 + kk * 1024);
#pragma unroll
    for (int ni = 0; ni < 2; ++ni)
#pragma unroll
      for (int kk = 0; kk < 2; ++kk)
        fb[ni][kk] = *(const bf16x8*)(brd + ni * 2048 + kk * 1024);
    if (st1) STG_B(nbuf, 1, t + 1);
    asm volatile("s_waitcnt lgkmcnt(8)" ::: "memory");  // smooth 12-read burst
    __builtin_amdgcn_s_barrier();
    MFMA_Q(0, 0);
    __builtin_amdgcn_s_barrier();

    // P2: (m-lo, n-hi); 4 ds_reads
#pragma unroll
    for (int ni = 2; ni < 4; ++ni)
#pragma unroll
      for (int kk = 0; kk < 2; ++kk)
        fb[ni][kk] = *(const bf16x8*)(brd + ni * 2048 + kk * 1024);
    __builtin_amdgcn_s_barrier();
    MFMA_Q(0, 2);
    __builtin_amdgcn_s_barrier();

    // P3: (m-hi, n-lo); 8 ds_reads
#pragma unroll
    for (int mi = 0; mi < 4; ++mi)
#pragma unroll
      for (int kk = 0; kk < 2; ++kk)
        fa[mi][kk] = *(const bf16x8*)(ard + (mi + 4) * 2048 + kk * 1024);
    if (st2) STG_B(buf, 0, t + 2);
    __builtin_amdgcn_s_barrier();
    MFMA_Q(4, 0);
    __builtin_amdgcn_s_barrier();

    // P4: (m-hi, n-hi); 0 ds_reads
    if (st2) { STG_A(buf, 0, t + 2); STG_A(buf, 1, t + 2); }
    __builtin_amdgcn_s_barrier();
    MFMA_Q(4, 2);
    if (st2) asm volatile("s_waitcnt vmcnt(6)" ::: "memory");
    else     asm volatile("s_waitcnt vmcnt(0)" ::: "memory");
    __builtin_amdgcn_s_barrier();     // tile t+1 fully resident past here
  }

  // ---- fused LSTM epilogue (2 passes, both LDS halves) ----
  // acc (mi,ni,q): row = wr*128 + mi*16 + l4*4 + q, col n' = wc*64+ni*16+l15,
  // hc = n'>>2, g = n'&3. Pass p: rows wr*128+p*64+[0,64) into LDS half wr.
  // LDS half wr: byte = rr*1024 + ((hc^rr)*16) + g*4.
  const int hc0 = n0 >> 2;
  const int ehc = tid & 63;
  const int err0 = (tid >> 6) * 8;
  const float bI = bi[hc0 + ehc];
  const float bF = bfg[hc0 + ehc];
  const float bO = bo[hc0 + ehc];
  const float bC = bc[hc0 + ehc];

  for (int p = 0; p < 2; ++p) {
    __builtin_amdgcn_s_barrier();
    {
      float* dst = (float*)(lds + wr * 65536);
      const int mib = p * 4;
#pragma unroll
      for (int mi = 0; mi < 4; ++mi)
#pragma unroll
        for (int ni = 0; ni < 4; ++ni) {
          const int col = wc * 64 + ni * 16 + l15;
          const int hc = col >> 2, g = col & 3;
#pragma unroll
          for (int q = 0; q < 4; ++q) {
            const int rr = mi * 16 + l4 * 4 + q;
            dst[rr * 256 + ((hc ^ rr) * 4) + g] = acc[mib + mi][ni][q];
          }
        }
    }
    __builtin_amdgcn_s_barrier();
#pragma unroll
    for (int half = 0; half < 2; ++half) {
      const float* src = (const float*)(lds + half * 65536);
#pragma unroll
      for (int r = 0; r < 8; ++r) {
        const int rr = err0 + r;
        f32x4 gq = *(const f32x4*)&src[rr * 256 + ((ehc ^ rr) * 4)];
        const size_t gidx =
            (size_t)(m0 + half * 128 + p * 64 + rr) * H_ + hc0 + ehc;
        float I = fsigmoid(gq[0] + bI);
        float F = fsigmoid(gq[1] + bF);
        float O = fsigmoid(gq[2] + bO);
        float Ct = ftanh(gq[3] + bC);
        float cn = F * c_in[gidx] + I * Ct;
        float hn = O * ftanh(cn);
        c_out[gidx] = cn;
        h_out[gidx] = hn;
        hb[gidx] = (bf16_t)hn;
      }
    }
  }
#undef STG_A
#undef STG_B
#undef MFMA_Q
}

// ---------------- GEMM2 (m97 structure, f32 out + bias) ----------------
__global__ __launch_bounds__(256) void gemm_bt_f32(
    const bf16_t* __restrict__ A, const bf16_t* __restrict__ Bt,
    float* __restrict__ Cout, const float* __restrict__ bias,
    int M, int N, int K) {
  __shared__ bf16_t As[128 * 64];
  __shared__ bf16_t Bs[128 * 64];
  const int tid = threadIdx.x;
  const int lane = tid & 63;
  const int wave = tid >> 6;
  const int m0 = blockIdx.y * 128;
  const int n0 = blockIdx.x * 128;
  const int wr = wave >> 1, wc = wave & 1;
  const int l15 = lane & 15, l4 = lane >> 4;

  f32x4 acc[4][4] = {};

  const int srow = tid >> 3;
  const int skel = (tid & 7) * 8;
  const size_t aBase = (size_t)(m0 + srow) * K + skel;
  const size_t bBase = (size_t)(n0 + srow) * K + skel;
  char* aL = (char*)As + wave * 1024;
  char* bL = (char*)Bs + wave * 1024;

  for (int kt = 0; kt < K; kt += 64) {
    __syncthreads();
#pragma unroll
    for (int i = 0; i < 4; ++i) {
      gload_lds16(A + aBase + (size_t)i * 32 * K + kt, aL + i * 4096);
      gload_lds16(Bt + bBase + (size_t)i * 32 * K + kt, bL + i * 4096);
    }
    __syncthreads();
#pragma unroll
    for (int kk = 0; kk < 2; ++kk) {
      bf16x8 af[4], bq[4];
#pragma unroll
      for (int mi = 0; mi < 4; ++mi)
        af[mi] = *(const bf16x8*)((const char*)As +
                 (wr * 64 + mi * 16 + l15) * 128 + kk * 64 + l4 * 16);
#pragma unroll
      for (int ni = 0; ni < 4; ++ni)
        bq[ni] = *(const bf16x8*)((const char*)Bs +
                 (wc * 64 + ni * 16 + l15) * 128 + kk * 64 + l4 * 16);
#pragma unroll
      for (int mi = 0; mi < 4; ++mi)
#pragma unroll
        for (int ni = 0; ni < 4; ++ni)
          acc[mi][ni] = __builtin_amdgcn_mfma_f32_16x16x32_bf16(
              af[mi], bq[ni], acc[mi][ni], 0, 0, 0);
    }
  }

  const int col = n0 + wc * 64 + l15;
  const int row0 = m0 + wr * 64 + l4 * 4;
#pragma unroll
  for (int ni = 0; ni < 4; ++ni) {
    const float bv = bias[col + ni * 16];
#pragma unroll
    for (int mi = 0; mi < 4; ++mi)
#pragma unroll
      for (int q = 0; q < 4; ++q)
        Cout[(size_t)(row0 + mi * 16 + q) * N + col + ni * 16] =
            acc[mi][ni][q] + bv;
  }
}

// ---------------- launcher ----------------
extern "C" void kernel_launch(void* const* d_in, const int* in_sizes, int n_in,
                              void* d_out, int out_size, void* d_ws,
                              size_t ws_size, hipStream_t stream) {
  const float* x = (const float*)d_in[0];
  const float* h = (const float*)d_in[1];
  const float* c = (const float*)d_in[2];
  const float* Wi = (const float*)d_in[3];
  const float* bi = (const float*)d_in[4];
  const float* Wf = (const float*)d_in[5];
  const float* bfg = (const float*)d_in[6];
  const float* Wo = (const float*)d_in[7];
  const float* bo = (const float*)d_in[8];
  const float* Wc = (const float*)d_in[9];
  const float* bc = (const float*)d_in[10];
  const float* Wy = (const float*)d_in[11];
  const float* by = (const float*)d_in[12];

  char* ws = (char*)d_ws;
  bf16_t* combined = (bf16_t*)ws;                       // 33.5 MB
  bf16_t* Wt = (bf16_t*)(ws + 33554432);                // 16.8 MB (interleaved)
  bf16_t* Wyt = (bf16_t*)(ws + 33554432 + 16777216);    // 1 MB
  bf16_t* hb = (bf16_t*)(ws + 33554432 + 16777216 + 1048576);  // 16.8 MB

  float* y_out = (float*)d_out;
  float* h_out = y_out + (size_t)B_ * OUT_;
  float* c_out = h_out + (size_t)B_ * H_;

  pack_combined<<<dim3(B_), dim3(256), 0, stream>>>(x, h, combined);
  transpose_pack4<<<dim3(H_ / 64, KC / 64, 4), dim3(256), 0, stream>>>(
      Wi, Wf, Wo, Wc, Wt);
  transpose_pack<<<dim3(OUT_ / 64, H_ / 64), dim3(256), 0, stream>>>(
      Wy, Wyt, H_, OUT_);

  gemm1_8ph<<<dim3((B_ / 256) * (N4 / 256)), dim3(512), 0, stream>>>(
      combined, Wt, c, bi, bfg, bo, bc, h_out, c_out, hb);

  gemm_bt_f32<<<dim3(OUT_ / 128, B_ / 128), dim3(256), 0, stream>>>(
      hb, Wyt, y_out, by, B_, OUT_, H_);
}

// Round 7
// 185.932 us; speedup vs baseline: 1.0615x; 1.0615x over previous
//
#include <hip/hip_runtime.h>
#include <hip/hip_bf16.h>
#include <stdint.h>

#define B_ 8192
#define IN_ 1024
#define H_ 1024
#define OUT_ 512
#define KC 2048   // IN_+H_
#define N4 4096   // 4*H_

typedef __bf16 bf16_t;
typedef __bf16 bf16x8 __attribute__((ext_vector_type(8)));
typedef float f32x4 __attribute__((ext_vector_type(4)));

__device__ __forceinline__ void gload_lds16(const void* g, void* l) {
  __builtin_amdgcn_global_load_lds(
      (const __attribute__((address_space(1))) uint32_t*)g,
      (__attribute__((address_space(3))) uint32_t*)l, 16, 0, 0);
}

__device__ __forceinline__ float fsigmoid(float x) {
  return __builtin_amdgcn_rcpf(1.0f + __expf(-x));
}
__device__ __forceinline__ float ftanh(float x) {
  return 2.0f * __builtin_amdgcn_rcpf(1.0f + __expf(-2.0f * x)) - 1.0f;
}

// ---------------- pack kernels ----------------

__global__ __launch_bounds__(256) void pack_combined(
    const float* __restrict__ x, const float* __restrict__ h,
    bf16_t* __restrict__ out) {
  const int row = blockIdx.x;
  const int j = threadIdx.x * 8;
  const float* src = (j < IN_) ? (x + (size_t)row * IN_ + j)
                               : (h + (size_t)row * H_ + (j - IN_));
  float4 a = ((const float4*)src)[0];
  float4 b = ((const float4*)src)[1];
  bf16x8 v;
  v[0] = (bf16_t)a.x; v[1] = (bf16_t)a.y; v[2] = (bf16_t)a.z; v[3] = (bf16_t)a.w;
  v[4] = (bf16_t)b.x; v[5] = (bf16_t)b.y; v[6] = (bf16_t)b.z; v[7] = (bf16_t)b.w;
  *(bf16x8*)(out + (size_t)row * KC + j) = v;
}

// One launch for all weight transposes.
// z<4: gate weight g -> dst row n*4+g, K=KC, N=H_ (src stride H_).
// z==4: Wy -> dst row n, K=H_, N=OUT_ (only bx<8, by<16 active).
__global__ __launch_bounds__(256) void transpose_all(
    const float* __restrict__ Wi, const float* __restrict__ Wf,
    const float* __restrict__ Wo, const float* __restrict__ Wc,
    const float* __restrict__ Wy, bf16_t* __restrict__ dstG,
    bf16_t* __restrict__ dstY) {
  const int z = blockIdx.z;
  const float* src;
  bf16_t* dst;
  int K, N, RS, RO;
  if (z < 4) {
    src = (z == 0) ? Wi : (z == 1) ? Wf : (z == 2) ? Wo : Wc;
    dst = dstG; K = KC; N = H_; RS = 4; RO = z;
  } else {
    if (blockIdx.x >= 8 || blockIdx.y >= 16) return;
    src = Wy; dst = dstY; K = H_; N = OUT_; RS = 1; RO = 0;
  }
  __shared__ float tile[64][65];
  const int k0 = blockIdx.y * 64, n0 = blockIdx.x * 64;
  const int t = threadIdx.x;
  const int tr = t >> 4, tc4 = (t & 15) * 4;
#pragma unroll
  for (int r = 0; r < 4; ++r) {
    const int k = tr + r * 16;
    float4 v = *(const float4*)(src + (size_t)(k0 + k) * N + n0 + tc4);
    tile[k][tc4] = v.x; tile[k][tc4 + 1] = v.y;
    tile[k][tc4 + 2] = v.z; tile[k][tc4 + 3] = v.w;
  }
  __syncthreads();
  const int nr = t >> 3, kc8 = (t & 7) * 8;
#pragma unroll
  for (int r = 0; r < 2; ++r) {
    const int n = nr + r * 32;
    bf16x8 v;
#pragma unroll
    for (int q = 0; q < 8; ++q) v[q] = (bf16_t)tile[kc8 + q][n];
    *(bf16x8*)(dst + (size_t)((n0 + n) * RS + RO) * K + k0 + kc8) = v;
  }
}

// ---------------- GEMM1: 256x256, 1 barrier/K-tile, fused LSTM epilogue ----
// (R5 structure — fastest measured: free-run tile, all staging to other buf)
__global__ __launch_bounds__(512) void gemm1_8ph(
    const bf16_t* __restrict__ A, const bf16_t* __restrict__ Bt,
    const float* __restrict__ c_in,
    const float* __restrict__ bi, const float* __restrict__ bfg,
    const float* __restrict__ bo, const float* __restrict__ bc,
    float* __restrict__ h_out, float* __restrict__ c_out,
    bf16_t* __restrict__ hb) {
  constexpr int K = KC;
  constexpr int NT = K / 64;  // 32 K-tiles
  __shared__ char lds[131072];

  const int tid = threadIdx.x;
  const int lane = tid & 63;
  const int w = tid >> 6;
  const int wr = w >> 2, wc = w & 3;
  const int l15 = lane & 15, l4 = lane >> 4;

  // XCD-bijective swizzle: 512 blocks, 8 XCDs, 64 blocks/XCD.
  const int wg = blockIdx.x;
  const int swz = (wg & 7) * 64 + (wg >> 3);
  const int bx = swz >> 5;   // 0..15
  const int by = swz & 31;   // 0..31
  const int m0 = by * 256, n0 = bx * 256;

  // ---- staging: per-lane pre-swizzled global source ----
  const int jrow = lane >> 2;
  const int jcol = ((lane & 3) * 16) ^ ((lane >> 5) << 5);
  const char* Asrc = (const char*)A + (size_t)(m0 + w * 16 + jrow) * (K * 2) + jcol;
  const char* Bsrc = (const char*)Bt + (size_t)(n0 + w * 16 + jrow) * (K * 2) + jcol;
  char* ldsA = lds;
  char* ldsB = lds + 32768;
  const int wchunk = w * 2048;

#define STG_A(buf, h, tt) do {                                            \
    gload_lds16(Asrc + (size_t)(h) * 128 * (K * 2) + (size_t)(tt) * 128,  \
                ldsA + (buf) * 65536 + (h) * 16384 + wchunk);             \
    gload_lds16(Asrc + (size_t)(h) * 128 * (K * 2) + (size_t)(tt) * 128 + 64, \
                ldsA + (buf) * 65536 + (h) * 16384 + wchunk + 1024);      \
  } while (0)
#define STG_B(buf, h, tt) do {                                            \
    gload_lds16(Bsrc + (size_t)(h) * 128 * (K * 2) + (size_t)(tt) * 128,  \
                ldsB + (buf) * 65536 + (h) * 16384 + wchunk);             \
    gload_lds16(Bsrc + (size_t)(h) * 128 * (K * 2) + (size_t)(tt) * 128 + 64, \
                ldsB + (buf) * 65536 + (h) * 16384 + wchunk + 1024);      \
  } while (0)

  const int rdoff = l15 * 64 + ((l4 * 16) ^ ((l15 >> 3) << 5));
  const char* ldsArd = lds + wr * 16384 + rdoff;
  const char* ldsBrd = lds + 32768 + (wc >> 1) * 16384 + (wc & 1) * 8192 + rdoff;

  f32x4 acc[8][4] = {};
  bf16x8 falo[4][2], fahi[4][2], fb[4][2];

  // ---- prologue: tile 0 into buf 0 ----
  STG_B(0, 0, 0); STG_B(0, 1, 0); STG_A(0, 0, 0); STG_A(0, 1, 0);
  asm volatile("s_waitcnt vmcnt(0)" ::: "memory");
  __builtin_amdgcn_s_barrier();

  for (int t = 0; t < NT; ++t) {
    const int buf = t & 1;
    const int nbuf = buf ^ 1;
    const char* ard = ldsArd + buf * 65536;
    const char* brd = ldsBrd + buf * 65536;
    const bool st1 = (t + 1 < NT);

    // batch 1 (8 reads): falo[0..1], fb[0..1]
#pragma unroll
    for (int mi = 0; mi < 2; ++mi)
#pragma unroll
      for (int kk = 0; kk < 2; ++kk)
        falo[mi][kk] = *(const bf16x8*)(ard + mi * 2048 + kk * 1024);
#pragma unroll
    for (int ni = 0; ni < 2; ++ni)
#pragma unroll
      for (int kk = 0; kk < 2; ++kk)
        fb[ni][kk] = *(const bf16x8*)(brd + ni * 2048 + kk * 1024);

    // stage tile t+1 into the other buffer (8 gloads)
    if (st1) {
      STG_B(nbuf, 0, t + 1); STG_B(nbuf, 1, t + 1);
      STG_A(nbuf, 0, t + 1); STG_A(nbuf, 1, t + 1);
    }

    // batch 2 (8 reads): falo[2..3], fb[2..3]
#pragma unroll
    for (int mi = 2; mi < 4; ++mi)
#pragma unroll
      for (int kk = 0; kk < 2; ++kk)
        falo[mi][kk] = *(const bf16x8*)(ard + mi * 2048 + kk * 1024);
#pragma unroll
    for (int ni = 2; ni < 4; ++ni)
#pragma unroll
      for (int kk = 0; kk < 2; ++kk)
        fb[ni][kk] = *(const bf16x8*)(brd + ni * 2048 + kk * 1024);

    // batch 3 (8 reads): fahi[0..3]
#pragma unroll
    for (int mi = 0; mi < 4; ++mi)
#pragma unroll
      for (int kk = 0; kk < 2; ++kk)
        fahi[mi][kk] = *(const bf16x8*)(ard + (mi + 4) * 2048 + kk * 1024);

    // C0 (8): falo01 x fb01
    __builtin_amdgcn_s_setprio(1);
#pragma unroll
    for (int kk = 0; kk < 2; ++kk)
#pragma unroll
      for (int mi = 0; mi < 2; ++mi)
#pragma unroll
        for (int ni = 0; ni < 2; ++ni)
          acc[mi][ni] = __builtin_amdgcn_mfma_f32_16x16x32_bf16(
              falo[mi][kk], fb[ni][kk], acc[mi][ni], 0, 0, 0);

    // C1 (16): falo01 x fb23 + falo23 x fb01
#pragma unroll
    for (int kk = 0; kk < 2; ++kk) {
#pragma unroll
      for (int mi = 0; mi < 2; ++mi)
#pragma unroll
        for (int ni = 2; ni < 4; ++ni)
          acc[mi][ni] = __builtin_amdgcn_mfma_f32_16x16x32_bf16(
              falo[mi][kk], fb[ni][kk], acc[mi][ni], 0, 0, 0);
#pragma unroll
      for (int mi = 2; mi < 4; ++mi)
#pragma unroll
        for (int ni = 0; ni < 2; ++ni)
          acc[mi][ni] = __builtin_amdgcn_mfma_f32_16x16x32_bf16(
              falo[mi][kk], fb[ni][kk], acc[mi][ni], 0, 0, 0);
    }

    // C2 (8): falo23 x fb23
#pragma unroll
    for (int kk = 0; kk < 2; ++kk)
#pragma unroll
      for (int mi = 2; mi < 4; ++mi)
#pragma unroll
        for (int ni = 2; ni < 4; ++ni)
          acc[mi][ni] = __builtin_amdgcn_mfma_f32_16x16x32_bf16(
              falo[mi][kk], fb[ni][kk], acc[mi][ni], 0, 0, 0);

    // C3 (32): fahi x fb (all)
#pragma unroll
    for (int kk = 0; kk < 2; ++kk)
#pragma unroll
      for (int mi = 0; mi < 4; ++mi)
#pragma unroll
        for (int ni = 0; ni < 4; ++ni)
          acc[mi + 4][ni] = __builtin_amdgcn_mfma_f32_16x16x32_bf16(
              fahi[mi][kk], fb[ni][kk], acc[mi + 4][ni], 0, 0, 0);
    __builtin_amdgcn_s_setprio(0);

    if (st1) asm volatile("s_waitcnt vmcnt(0)" ::: "memory");
    __builtin_amdgcn_s_barrier();  // tile t+1 resident; buf roles swap
  }

  // ---- fused LSTM epilogue (2 passes, both LDS halves) ----
  const int hc0 = n0 >> 2;
  const int ehc = tid & 63;
  const int err0 = (tid >> 6) * 8;
  const float bI = bi[hc0 + ehc];
  const float bF = bfg[hc0 + ehc];
  const float bO = bo[hc0 + ehc];
  const float bC = bc[hc0 + ehc];

  // prefetch c_in for all 32 elements this thread owns (latency hides under
  // the LDS dump + pass-0 transcendentals)
  float cpre[2][2][8];
#pragma unroll
  for (int p = 0; p < 2; ++p)
#pragma unroll
    for (int half = 0; half < 2; ++half)
#pragma unroll
      for (int r = 0; r < 8; ++r)
        cpre[p][half][r] =
            c_in[(size_t)(m0 + half * 128 + p * 64 + err0 + r) * H_ + hc0 + ehc];

  for (int p = 0; p < 2; ++p) {
    __builtin_amdgcn_s_barrier();
    {
      float* dst = (float*)(lds + wr * 65536);
      const int mib = p * 4;
#pragma unroll
      for (int mi = 0; mi < 4; ++mi)
#pragma unroll
        for (int ni = 0; ni < 4; ++ni) {
          const int col = wc * 64 + ni * 16 + l15;
          const int hc = col >> 2, g = col & 3;
#pragma unroll
          for (int q = 0; q < 4; ++q) {
            const int rr = mi * 16 + l4 * 4 + q;
            dst[rr * 256 + ((hc ^ rr) * 4) + g] = acc[mib + mi][ni][q];
          }
        }
    }
    __builtin_amdgcn_s_barrier();
#pragma unroll
    for (int half = 0; half < 2; ++half) {
      const float* src = (const float*)(lds + half * 65536);
#pragma unroll
      for (int r = 0; r < 8; ++r) {
        const int rr = err0 + r;
        f32x4 gq = *(const f32x4*)&src[rr * 256 + ((ehc ^ rr) * 4)];
        const size_t gidx =
            (size_t)(m0 + half * 128 + p * 64 + rr) * H_ + hc0 + ehc;
        float I = fsigmoid(gq[0] + bI);
        float F = fsigmoid(gq[1] + bF);
        float O = fsigmoid(gq[2] + bO);
        float Ct = ftanh(gq[3] + bC);
        float cn = F * cpre[p][half][r] + I * Ct;
        float hn = O * ftanh(cn);
        c_out[gidx] = cn;
        h_out[gidx] = hn;
        hb[gidx] = (bf16_t)hn;
      }
    }
  }
#undef STG_A
#undef STG_B
}

// ---------------- GEMM2 (m97 structure + LDS swizzle, f32 out + bias) ------
__global__ __launch_bounds__(256) void gemm_bt_f32(
    const bf16_t* __restrict__ A, const bf16_t* __restrict__ Bt,
    float* __restrict__ Cout, const float* __restrict__ bias,
    int M, int N, int K) {
  __shared__ bf16_t As[128 * 64];
  __shared__ bf16_t Bs[128 * 64];
  const int tid = threadIdx.x;
  const int lane = tid & 63;
  const int wave = tid >> 6;
  const int m0 = blockIdx.y * 128;
  const int n0 = blockIdx.x * 128;
  const int wr = wave >> 1, wc = wave & 1;
  const int l15 = lane & 15, l4 = lane >> 4;

  f32x4 acc[4][4] = {};

  // staging: pre-swizzled global k-byte so linear LDS dest holds swizzled data
  const int srow = tid >> 3;
  const int slot = tid & 7;
  const int skelb = (slot * 16) ^ ((srow & 7) << 4);
  const char* aSrc = (const char*)A + (size_t)(m0 + srow) * (K * 2) + skelb;
  const char* bSrc = (const char*)Bt + (size_t)(n0 + srow) * (K * 2) + skelb;
  char* aL = (char*)As + wave * 1024;
  char* bL = (char*)Bs + wave * 1024;

  const int xr = (l15 & 7) << 4;  // read-side XOR (row&7 == l15&7)

  for (int kt = 0; kt < K; kt += 64) {
    __syncthreads();
#pragma unroll
    for (int i = 0; i < 4; ++i) {
      gload_lds16(aSrc + ((size_t)i * 32 * K + kt) * 2, aL + i * 4096);
      gload_lds16(bSrc + ((size_t)i * 32 * K + kt) * 2, bL + i * 4096);
    }
    __syncthreads();
#pragma unroll
    for (int kk = 0; kk < 2; ++kk) {
      bf16x8 af[4], bq[4];
#pragma unroll
      for (int mi = 0; mi < 4; ++mi)
        af[mi] = *(const bf16x8*)((const char*)As +
                 (wr * 64 + mi * 16 + l15) * 128 + ((kk * 64 + l4 * 16) ^ xr));
#pragma unroll
      for (int ni = 0; ni < 4; ++ni)
        bq[ni] = *(const bf16x8*)((const char*)Bs +
                 (wc * 64 + ni * 16 + l15) * 128 + ((kk * 64 + l4 * 16) ^ xr));
#pragma unroll
      for (int mi = 0; mi < 4; ++mi)
#pragma unroll
        for (int ni = 0; ni < 4; ++ni)
          acc[mi][ni] = __builtin_amdgcn_mfma_f32_16x16x32_bf16(
              af[mi], bq[ni], acc[mi][ni], 0, 0, 0);
    }
  }

  const int col = n0 + wc * 64 + l15;
  const int row0 = m0 + wr * 64 + l4 * 4;
#pragma unroll
  for (int ni = 0; ni < 4; ++ni) {
    const float bv = bias[col + ni * 16];
#pragma unroll
    for (int mi = 0; mi < 4; ++mi)
#pragma unroll
      for (int q = 0; q < 4; ++q)
        Cout[(size_t)(row0 + mi * 16 + q) * N + col + ni * 16] =
            acc[mi][ni][q] + bv;
  }
}

// ---------------- launcher ----------------
extern "C" void kernel_launch(void* const* d_in, const int* in_sizes, int n_in,
                              void* d_out, int out_size, void* d_ws,
                              size_t ws_size, hipStream_t stream) {
  const float* x = (const float*)d_in[0];
  const float* h = (const float*)d_in[1];
  const float* c = (const float*)d_in[2];
  const float* Wi = (const float*)d_in[3];
  const float* bi = (const float*)d_in[4];
  const float* Wf = (const float*)d_in[5];
  const float* bfg = (const float*)d_in[6];
  const float* Wo = (const float*)d_in[7];
  const float* bo = (const float*)d_in[8];
  const float* Wc = (const float*)d_in[9];
  const float* bc = (const float*)d_in[10];
  const float* Wy = (const float*)d_in[11];
  const float* by = (const float*)d_in[12];

  char* ws = (char*)d_ws;
  bf16_t* combined = (bf16_t*)ws;                       // 33.5 MB
  bf16_t* Wt = (bf16_t*)(ws + 33554432);                // 16.8 MB (interleaved)
  bf16_t* Wyt = (bf16_t*)(ws + 33554432 + 16777216);    // 1 MB
  bf16_t* hb = (bf16_t*)(ws + 33554432 + 16777216 + 1048576);  // 16.8 MB

  float* y_out = (float*)d_out;
  float* h_out = y_out + (size_t)B_ * OUT_;
  float* c_out = h_out + (size_t)B_ * H_;

  pack_combined<<<dim3(B_), dim3(256), 0, stream>>>(x, h, combined);
  transpose_all<<<dim3(16, 32, 5), dim3(256), 0, stream>>>(
      Wi, Wf, Wo, Wc, Wy, Wt, Wyt);

  gemm1_8ph<<<dim3((B_ / 256) * (N4 / 256)), dim3(512), 0, stream>>>(
      combined, Wt, c, bi, bfg, bo, bc, h_out, c_out, hb);

  gemm_bt_f32<<<dim3(OUT_ / 128, B_ / 128), dim3(256), 0, stream>>>(
      hb, Wyt, y_out, by, B_, OUT_, H_);
}